// Round 7
// baseline (507.626 us; speedup 1.0000x reference)
//
#include <hip/hip_runtime.h>
#include <math.h>

#define NT 16384
#define HID 2048
#define NE 256
#define NG 8
#define TOPG 4
#define TOPKK 8

constexpr int BM = 32;   // tokens per block
constexpr int KC = 16;   // K chunk (R2's proven cadence — do not change)

// ---------------------------------------------------------------------------
// Fused kernel: scores = sigmoid(x @ W^T + bias), then grouped top-k routing,
// all in one kernel. Main GEMM loop is bit-identical to the round-2 kernel
// that measured VALUBusy 88% / 234 us. Epilogue: each 32-lane half-wave
// (fixed ty) holds the full 256-expert row for 4 tokens (8 f64/lane) and
// routes them in-register via <=16-wide shuffle butterflies.
// ---------------------------------------------------------------------------
__global__ __launch_bounds__(256) void score_route_kernel(
    const float* __restrict__ x, const float* __restrict__ w,
    const float* __restrict__ bias,
    float* __restrict__ wout, float* __restrict__ iout)
{
    __shared__ float xs[KC][BM];    // 2 KB, transposed: xs[k][token]
    __shared__ float wsm[KC][NE];   // 16 KB, transposed: wsm[k][expert]

    const int tid = threadIdx.x;
    const int tx = tid & 31;        // expert-column group
    const int ty = tid >> 5;        // token-row group (0..7), 4 rows each
    const int m0 = blockIdx.x * BM;

    double accd[4][8];
#pragma unroll
    for (int mi = 0; mi < 4; mi++)
#pragma unroll
        for (int j = 0; j < 8; j++) accd[mi][j] = 0.0;

    const int xrow = tid & 31;      // token row for x staging
    const int xkp  = tid >> 5;      // k-pair index 0..7

    // ------------------ main loop: VERBATIM round-2 structure ------------------
    for (int k0 = 0; k0 < HID; k0 += KC) {
        const float* wrow = w + (size_t)tid * HID + k0;
        float4 wv0 = *(const float4*)(wrow + 0);
        float4 wv1 = *(const float4*)(wrow + 4);
        float4 wv2 = *(const float4*)(wrow + 8);
        float4 wv3 = *(const float4*)(wrow + 12);
        float2 xv  = *(const float2*)(x + (size_t)(m0 + xrow) * HID + k0 + xkp * 2);

        __syncthreads();   // previous iteration's reads done

        wsm[ 0][tid] = wv0.x; wsm[ 1][tid] = wv0.y; wsm[ 2][tid] = wv0.z; wsm[ 3][tid] = wv0.w;
        wsm[ 4][tid] = wv1.x; wsm[ 5][tid] = wv1.y; wsm[ 6][tid] = wv1.z; wsm[ 7][tid] = wv1.w;
        wsm[ 8][tid] = wv2.x; wsm[ 9][tid] = wv2.y; wsm[10][tid] = wv2.z; wsm[11][tid] = wv2.w;
        wsm[12][tid] = wv3.x; wsm[13][tid] = wv3.y; wsm[14][tid] = wv3.z; wsm[15][tid] = wv3.w;
        xs[xkp * 2    ][xrow] = xv.x;
        xs[xkp * 2 + 1][xrow] = xv.y;

        __syncthreads();

        float accf[4][8];
#pragma unroll
        for (int mi = 0; mi < 4; mi++)
#pragma unroll
            for (int j = 0; j < 8; j++) accf[mi][j] = 0.0f;

#pragma unroll
        for (int kk = 0; kk < KC; kk++) {
            float4 a  = *(const float4*)&xs[kk][ty * 4];
            float4 b0 = *(const float4*)&wsm[kk][tx * 4];
            float4 b1 = *(const float4*)&wsm[kk][128 + tx * 4];
            float av[4] = {a.x, a.y, a.z, a.w};
            float bv[8] = {b0.x, b0.y, b0.z, b0.w, b1.x, b1.y, b1.z, b1.w};
#pragma unroll
            for (int mi = 0; mi < 4; mi++)
#pragma unroll
                for (int j = 0; j < 8; j++)
                    accf[mi][j] = fmaf(av[mi], bv[j], accf[mi][j]);
        }

#pragma unroll
        for (int mi = 0; mi < 4; mi++)
#pragma unroll
            for (int j = 0; j < 8; j++) accd[mi][j] += (double)accf[mi][j];
    }

    // ------------------ fused routing epilogue (in-register) ------------------
    // Half-wave = lanes sharing ty. Lane tx owns experts {4tx..4tx+3} (slots
    // 0..3) and {128+4tx..128+4tx+3} (slots 4..7). Group g<4 <-> lanes 8g..8g+7
    // slots 0..3; group g>=4 <-> lanes 8(g-4).. slots 4..7.
    const double NEG = -__builtin_inf();
    const int base = (tid & 63) & 32;   // my half's base lane within the wave

    // expert-column bias values (same for all 4 tokens)
    float bj[8];
#pragma unroll
    for (int j = 0; j < 8; j++) {
        const int n = (j < 4) ? (tx * 4 + j) : (128 + tx * 4 + (j - 4));
        bj[j] = bias[n];
    }

#pragma unroll
    for (int mi = 0; mi < 4; mi++) {
        const int tok = m0 + ty * 4 + mi;

        double sg[8], sb[8];
#pragma unroll
        for (int j = 0; j < 8; j++) {
            double z = accd[mi][j] + (double)bj[j];
            double s = 1.0 / (1.0 + exp(-z));
            sg[j] = s;
            sb[j] = s + (double)bj[j];
        }

        // per-lane top-2 within each quad (proven sequence)
        double m1lo = sb[0], m2lo = NEG;
        if (sb[1] > m1lo) { m2lo = m1lo; m1lo = sb[1]; } else if (sb[1] > m2lo) m2lo = sb[1];
        if (sb[2] > m1lo) { m2lo = m1lo; m1lo = sb[2]; } else if (sb[2] > m2lo) m2lo = sb[2];
        if (sb[3] > m1lo) { m2lo = m1lo; m1lo = sb[3]; } else if (sb[3] > m2lo) m2lo = sb[3];
        double m1hi = sb[4], m2hi = NEG;
        if (sb[5] > m1hi) { m2hi = m1hi; m1hi = sb[5]; } else if (sb[5] > m2hi) m2hi = sb[5];
        if (sb[6] > m1hi) { m2hi = m1hi; m1hi = sb[6]; } else if (sb[6] > m2hi) m2hi = sb[6];
        if (sb[7] > m1hi) { m2hi = m1hi; m1hi = sb[7]; } else if (sb[7] > m2hi) m2hi = sb[7];

        // 8-lane butterfly merge of top-2 pairs (masks stay within half-wave)
#pragma unroll
        for (int mask = 1; mask <= 4; mask <<= 1) {
            double o1 = __shfl_xor(m1lo, mask);
            double o2 = __shfl_xor(m2lo, mask);
            double n1 = fmax(m1lo, o1);
            double n2 = fmax(fmin(m1lo, o1), fmax(m2lo, o2));
            m1lo = n1; m2lo = n2;
            o1 = __shfl_xor(m1hi, mask);
            o2 = __shfl_xor(m2hi, mask);
            n1 = fmax(m1hi, o1);
            n2 = fmax(fmin(m1hi, o1), fmax(m2hi, o2));
            m1hi = n1; m2hi = n2;
        }
        const double gs_lo = m1lo + m2lo;   // group tx>>3
        const double gs_hi = m1hi + m2hi;   // group 4+(tx>>3)

        // gather all 8 group scores
        double g[8];
#pragma unroll
        for (int q = 0; q < 4; q++) {
            g[q]     = __shfl(gs_lo, base + 8 * q);
            g[4 + q] = __shfl(gs_hi, base + 8 * q);
        }

        const int glo = tx >> 3;
        const int ghi = 4 + glo;
        int rank_lo = 0, rank_hi = 0;
#pragma unroll
        for (int q = 0; q < 8; q++) {
            rank_lo += (g[q] > g[glo] || (g[q] == g[glo] && q < glo)) ? 1 : 0;
            rank_hi += (g[q] > g[ghi] || (g[q] == g[ghi] && q < ghi)) ? 1 : 0;
        }
        const bool keep_lo = (rank_lo < TOPG);
        const bool keep_hi = (rank_hi < TOPG);

        double v[8];
#pragma unroll
        for (int j = 0; j < 8; j++)
            v[j] = ((j < 4) ? keep_lo : keep_hi) ? sb[j] : NEG;

        double wv[TOPKK];
        int    idx[TOPKK];

#pragma unroll
        for (int r = 0; r < TOPKK; r++) {
            // per-lane argmax over 8 slots (ascending j + strict > => lowest idx)
            double bv = v[0]; int bi = tx * 4;
#pragma unroll
            for (int j = 1; j < 8; j++) {
                const int ej = (j < 4) ? (tx * 4 + j) : (128 + tx * 4 + (j - 4));
                if (v[j] > bv) { bv = v[j]; bi = ej; }
            }
            // 32-lane butterfly argmax (within half), tie -> lowest expert idx
#pragma unroll
            for (int mask = 1; mask <= 16; mask <<= 1) {
                double ov = __shfl_xor(bv, mask);
                int    oi = __shfl_xor(bi, mask);
                if (ov > bv || (ov == bv && oi < bi)) { bv = ov; bi = oi; }
            }
            // winner: expert bi. owner lane tx_o, slot within owner
            const int tx_o = (bi & 127) >> 2;
            const int slot = (bi < 128) ? (bi & 3) : (4 + (bi & 3));
            // fetch winner's ORIGINAL sigmoid score
            double mysig = sg[0];
#pragma unroll
            for (int j = 1; j < 8; j++)
                if (j == slot) mysig = sg[j];
            wv[r]  = __shfl(mysig, base + tx_o);
            idx[r] = bi;
            // knock out the winner
#pragma unroll
            for (int j = 0; j < 8; j++)
                if (tx == tx_o && j == slot) v[j] = NEG;
        }

        double sum = 0.0;
#pragma unroll
        for (int r = 0; r < TOPKK; r++) sum += wv[r];
        const double scale = 2.5 / sum;

        if (tx == 0) {
#pragma unroll
            for (int r = 0; r < TOPKK; r++)
                wout[(size_t)tok * TOPKK + r] = (float)(wv[r] * scale);
#pragma unroll
            for (int r = 0; r < TOPKK; r++)
                iout[(size_t)tok * TOPKK + r] = (float)idx[r];
        }
    }
}

// ---------------------------------------------------------------------------
extern "C" void kernel_launch(void* const* d_in, const int* in_sizes, int n_in,
                              void* d_out, int out_size, void* d_ws, size_t ws_size,
                              hipStream_t stream) {
    const float* x = (const float*)d_in[0];
    const float* w = (const float*)d_in[1];
    const float* b = (const float*)d_in[2];

    float* wout = (float*)d_out;                // [NT][8] weights
    float* iout = wout + (size_t)NT * TOPKK;    // [NT][8] indices stored as float

    score_route_kernel<<<NT / BM, 256, 0, stream>>>(x, w, b, wout, iout);
}

// Round 8
// 448.945 us; speedup vs baseline: 1.1307x; 1.1307x over previous
//
#include <hip/hip_runtime.h>
#include <math.h>

#define NT 16384
#define HID 2048
#define NE 256
#define NG 8
#define TOPG 4
#define TOPKK 8

constexpr int BM = 32;   // tokens per block
constexpr int KC = 16;   // K chunk (R2's proven cadence)

// ---------------------------------------------------------------------------
// Kernel A: scores = sigmoid(x @ W^T + bias) -> f64 [NT][NE] in ws.
// R2 structure verbatim; accumulation is two-level fp32 (per-chunk accf,
// rolled into persistent f32 accd). Reference is numpy fp32, and both R2's
// and R4's (~1e-6-different) rounding patterns gave zero index flips, so
// fp32 two-level (~1e-6 deviation) is within the demonstrated safety margin.
// Removes the 64-VGPR f64 accumulator that caused AGPR-parking glue (R4-R7).
// ---------------------------------------------------------------------------
__global__ __launch_bounds__(256) void score_kernel(
    const float* __restrict__ x, const float* __restrict__ w,
    const float* __restrict__ bias, double* __restrict__ sd)
{
    __shared__ float xs[KC][BM];    // 2 KB, transposed: xs[k][token]
    __shared__ float wsm[KC][NE];   // 16 KB, transposed: wsm[k][expert]

    const int tid = threadIdx.x;
    const int tx = tid & 31;        // expert-column group
    const int ty = tid >> 5;        // token-row group (0..7), 4 rows each
    const int m0 = blockIdx.x * BM;

    float accd[4][8];
#pragma unroll
    for (int mi = 0; mi < 4; mi++)
#pragma unroll
        for (int j = 0; j < 8; j++) accd[mi][j] = 0.0f;

    const int xrow = tid & 31;      // token row for x staging
    const int xkp  = tid >> 5;      // k-pair index 0..7

    for (int k0 = 0; k0 < HID; k0 += KC) {
        // global loads first (hide latency)
        const float* wrow = w + (size_t)tid * HID + k0;
        float4 wv0 = *(const float4*)(wrow + 0);
        float4 wv1 = *(const float4*)(wrow + 4);
        float4 wv2 = *(const float4*)(wrow + 8);
        float4 wv3 = *(const float4*)(wrow + 12);
        float2 xv  = *(const float2*)(x + (size_t)(m0 + xrow) * HID + k0 + xkp * 2);

        __syncthreads();   // previous iteration's reads done

        // stage W transposed: wsm[k][expert=tid]; 2-way bank alias (free)
        wsm[ 0][tid] = wv0.x; wsm[ 1][tid] = wv0.y; wsm[ 2][tid] = wv0.z; wsm[ 3][tid] = wv0.w;
        wsm[ 4][tid] = wv1.x; wsm[ 5][tid] = wv1.y; wsm[ 6][tid] = wv1.z; wsm[ 7][tid] = wv1.w;
        wsm[ 8][tid] = wv2.x; wsm[ 9][tid] = wv2.y; wsm[10][tid] = wv2.z; wsm[11][tid] = wv2.w;
        wsm[12][tid] = wv3.x; wsm[13][tid] = wv3.y; wsm[14][tid] = wv3.z; wsm[15][tid] = wv3.w;
        xs[xkp * 2    ][xrow] = xv.x;
        xs[xkp * 2 + 1][xrow] = xv.y;

        __syncthreads();

        float accf[4][8];

        // peeled kk = 0: multiply (replaces zero-init + fma)
        {
            float4 a  = *(const float4*)&xs[0][ty * 4];
            float4 b0 = *(const float4*)&wsm[0][tx * 4];
            float4 b1 = *(const float4*)&wsm[0][128 + tx * 4];
            float av[4] = {a.x, a.y, a.z, a.w};
            float bv[8] = {b0.x, b0.y, b0.z, b0.w, b1.x, b1.y, b1.z, b1.w};
#pragma unroll
            for (int mi = 0; mi < 4; mi++)
#pragma unroll
                for (int j = 0; j < 8; j++)
                    accf[mi][j] = av[mi] * bv[j];
        }

#pragma unroll
        for (int kk = 1; kk < KC; kk++) {
            float4 a  = *(const float4*)&xs[kk][ty * 4];          // broadcast
            float4 b0 = *(const float4*)&wsm[kk][tx * 4];
            float4 b1 = *(const float4*)&wsm[kk][128 + tx * 4];
            float av[4] = {a.x, a.y, a.z, a.w};
            float bv[8] = {b0.x, b0.y, b0.z, b0.w, b1.x, b1.y, b1.z, b1.w};
#pragma unroll
            for (int mi = 0; mi < 4; mi++)
#pragma unroll
                for (int j = 0; j < 8; j++)
                    accf[mi][j] = fmaf(av[mi], bv[j], accf[mi][j]);
        }

        // roll chunk into persistent f32 accumulators (two-level fp32)
#pragma unroll
        for (int mi = 0; mi < 4; mi++)
#pragma unroll
            for (int j = 0; j < 8; j++) accd[mi][j] += accf[mi][j];
    }

    // epilogue: add bias, sigmoid in f64, store f64 (routing stays proven)
#pragma unroll
    for (int mi = 0; mi < 4; mi++) {
        const size_t row = (size_t)(m0 + ty * 4 + mi) * NE;
#pragma unroll
        for (int j = 0; j < 8; j++) {
            const int n = (j < 4) ? (tx * 4 + j) : (128 + tx * 4 + (j - 4));
            double z = (double)accd[mi][j] + (double)bias[n];
            double s = 1.0 / (1.0 + exp(-z));
            sd[row + n] = s;
        }
    }
}

// ---------------------------------------------------------------------------
// Kernel B: grouped routing. One wave (64 lanes) per token; lane l owns
// experts [4l, 4l+3]; group g = experts [32g, 32g+31] = lanes [8g, 8g+7].
// (unchanged — proven correct since round 2)
// ---------------------------------------------------------------------------
__global__ __launch_bounds__(256) void route_kernel(
    const double* __restrict__ sd, const float* __restrict__ bias,
    float* __restrict__ wout, float* __restrict__ iout)
{
    const int lane = threadIdx.x & 63;
    const int wid  = threadIdx.x >> 6;
    const int tok  = blockIdx.x * 4 + wid;
    const double* srow = sd + (size_t)tok * NE;
    const int e0 = lane * 4;

    const double NEG = -__builtin_inf();

    double s0 = srow[e0 + 0], s1 = srow[e0 + 1], s2 = srow[e0 + 2], s3 = srow[e0 + 3];
    double sb0 = s0 + (double)bias[e0 + 0];
    double sb1 = s1 + (double)bias[e0 + 1];
    double sb2 = s2 + (double)bias[e0 + 2];
    double sb3 = s3 + (double)bias[e0 + 3];

    // per-lane top-2 of 4
    double m1 = sb0, m2 = NEG;
    if (sb1 > m1) { m2 = m1; m1 = sb1; } else if (sb1 > m2) m2 = sb1;
    if (sb2 > m1) { m2 = m1; m1 = sb2; } else if (sb2 > m2) m2 = sb2;
    if (sb3 > m1) { m2 = m1; m1 = sb3; } else if (sb3 > m2) m2 = sb3;

    // 8-lane butterfly merge of top-2 pairs (within group)
#pragma unroll
    for (int mask = 1; mask <= 4; mask <<= 1) {
        double o1 = __shfl_xor(m1, mask);
        double o2 = __shfl_xor(m2, mask);
        double n1 = fmax(m1, o1);
        double n2 = fmax(fmin(m1, o1), fmax(m2, o2));
        m1 = n1; m2 = n2;
    }
    double gs = m1 + m2;   // group score

    double g[8];
#pragma unroll
    for (int j = 0; j < 8; j++) g[j] = __shfl(gs, j * 8);

    const int myg = lane >> 3;
    int rank = 0;
#pragma unroll
    for (int j = 0; j < 8; j++)
        rank += (g[j] > g[myg] || (g[j] == g[myg] && j < myg)) ? 1 : 0;
    const bool keep = (rank < TOPG);

    double v0 = keep ? sb0 : NEG;
    double v1 = keep ? sb1 : NEG;
    double v2 = keep ? sb2 : NEG;
    double v3 = keep ? sb3 : NEG;

    double wv[TOPKK];
    int    idx[TOPKK];

#pragma unroll
    for (int r = 0; r < TOPKK; r++) {
        double bvv = v0; int bi = e0;
        if (v1 > bvv) { bvv = v1; bi = e0 + 1; }
        if (v2 > bvv) { bvv = v2; bi = e0 + 2; }
        if (v3 > bvv) { bvv = v3; bi = e0 + 3; }
#pragma unroll
        for (int mask = 1; mask <= 32; mask <<= 1) {
            double ov = __shfl_xor(bvv, mask);
            int    oi = __shfl_xor(bi, mask);
            if (ov > bvv || (ov == bvv && oi < bi)) { bvv = ov; bi = oi; }
        }
        const int sel   = bi & 3;
        const int owner = bi >> 2;
        double cands = (sel == 0) ? s0 : (sel == 1) ? s1 : (sel == 2) ? s2 : s3;
        wv[r]  = __shfl(cands, owner);
        idx[r] = bi;
        if (lane == owner) {
            if (sel == 0) v0 = NEG;
            else if (sel == 1) v1 = NEG;
            else if (sel == 2) v2 = NEG;
            else v3 = NEG;
        }
    }

    double sum = 0.0;
#pragma unroll
    for (int r = 0; r < TOPKK; r++) sum += wv[r];
    const double scale = 2.5 / sum;

    if (lane == 0) {
#pragma unroll
        for (int r = 0; r < TOPKK; r++)
            wout[(size_t)tok * TOPKK + r] = (float)(wv[r] * scale);
#pragma unroll
        for (int r = 0; r < TOPKK; r++)
            iout[(size_t)tok * TOPKK + r] = (float)idx[r];
    }
}

// ---------------------------------------------------------------------------
extern "C" void kernel_launch(void* const* d_in, const int* in_sizes, int n_in,
                              void* d_out, int out_size, void* d_ws, size_t ws_size,
                              hipStream_t stream) {
    const float* x = (const float*)d_in[0];
    const float* w = (const float*)d_in[1];
    const float* b = (const float*)d_in[2];

    double* sd = (double*)d_ws;                 // [NT][NE] f64 sigmoid scores (32 MB)
    float* wout = (float*)d_out;                // [NT][8] weights
    float* iout = wout + (size_t)NT * TOPKK;    // [NT][8] indices stored as float

    score_kernel<<<NT / BM, 256, 0, stream>>>(x, w, b, sd);
    route_kernel<<<NT / 4, 256, 0, stream>>>(sd, b, wout, iout);
}

// Round 9
// 415.126 us; speedup vs baseline: 1.2228x; 1.0815x over previous
//
#include <hip/hip_runtime.h>
#include <math.h>

#define NT 16384
#define HID 2048
#define NE 256
#define NG 8
#define TOPG 4
#define TOPKK 8

constexpr int BM = 64;   // tokens per block
constexpr int KC = 32;   // K chunk (64 chunks -> fewest barrier stalls, R4-proven)

// ---------------------------------------------------------------------------
// Kernel A: scores = sigmoid(x @ W^T + bias) -> f64 [NT][NE] in ws.
// Structure = R4 verbatim (best measured in current regime: 285 us), with
// fp32 two-level accumulation (proven safe in R8, absmax 0.0) replacing the
// f64 accumulators that cost ~9% VALU glue and 64 VGPRs of pressure.
// 512 threads: tx = expert-col group (0..31), ty = token-row group (0..15).
// Per-thread output tile: 4 rows x 8 cols; 1024 FMAs per chunk.
// ---------------------------------------------------------------------------
__global__ __launch_bounds__(512) void score_kernel(
    const float* __restrict__ x, const float* __restrict__ w,
    const float* __restrict__ bias, double* __restrict__ sd)
{
    __shared__ float xs[KC][BM];    // 8 KB, transposed: xs[k][token]
    __shared__ float wsm[KC][NE];   // 32 KB, transposed: wsm[k][expert]

    const int tid = threadIdx.x;
    const int tx = tid & 31;        // expert-column group
    const int ty = tid >> 5;        // token-row group (0..15), 4 rows each
    const int m0 = blockIdx.x * BM;

    // staging roles
    const int xrow = tid & 63;          // token row 0..63
    const int xko  = (tid >> 6) * 4;    // k-quad start 0,4,...,28
    const int wexp = tid & 255;         // expert 0..255
    const int wko  = (tid >> 8) * 16;   // k-half start 0 or 16

    float accd[4][8];
#pragma unroll
    for (int mi = 0; mi < 4; mi++)
#pragma unroll
        for (int j = 0; j < 8; j++) accd[mi][j] = 0.0f;

    const float* wbase = w + (size_t)wexp * HID + wko;
    const float* xbase = x + (size_t)(m0 + xrow) * HID + xko;

    for (int k0 = 0; k0 < HID; k0 += KC) {
        // global loads first (hide latency)
        float4 wv0 = *(const float4*)(wbase + k0 + 0);
        float4 wv1 = *(const float4*)(wbase + k0 + 4);
        float4 wv2 = *(const float4*)(wbase + k0 + 8);
        float4 wv3 = *(const float4*)(wbase + k0 + 12);
        float4 xv  = *(const float4*)(xbase + k0);

        __syncthreads();   // previous iteration's LDS reads done

        // stage W transposed: wsm[k][expert]; bank = wexp%32 -> 2-way (free)
        wsm[wko +  0][wexp] = wv0.x; wsm[wko +  1][wexp] = wv0.y;
        wsm[wko +  2][wexp] = wv0.z; wsm[wko +  3][wexp] = wv0.w;
        wsm[wko +  4][wexp] = wv1.x; wsm[wko +  5][wexp] = wv1.y;
        wsm[wko +  6][wexp] = wv1.z; wsm[wko +  7][wexp] = wv1.w;
        wsm[wko +  8][wexp] = wv2.x; wsm[wko +  9][wexp] = wv2.y;
        wsm[wko + 10][wexp] = wv2.z; wsm[wko + 11][wexp] = wv2.w;
        wsm[wko + 12][wexp] = wv3.x; wsm[wko + 13][wexp] = wv3.y;
        wsm[wko + 14][wexp] = wv3.z; wsm[wko + 15][wexp] = wv3.w;
        xs[xko + 0][xrow] = xv.x;
        xs[xko + 1][xrow] = xv.y;
        xs[xko + 2][xrow] = xv.z;
        xs[xko + 3][xrow] = xv.w;

        __syncthreads();

        float accf[4][8];

        // peeled kk = 0: multiply (replaces zero-init + fma)
        {
            float4 a  = *(const float4*)&xs[0][ty * 4];
            float4 b0 = *(const float4*)&wsm[0][tx * 4];
            float4 b1 = *(const float4*)&wsm[0][128 + tx * 4];
            float av[4] = {a.x, a.y, a.z, a.w};
            float bv[8] = {b0.x, b0.y, b0.z, b0.w, b1.x, b1.y, b1.z, b1.w};
#pragma unroll
            for (int mi = 0; mi < 4; mi++)
#pragma unroll
                for (int j = 0; j < 8; j++)
                    accf[mi][j] = av[mi] * bv[j];
        }

#pragma unroll
        for (int kk = 1; kk < KC; kk++) {
            float4 a  = *(const float4*)&xs[kk][ty * 4];          // broadcast
            float4 b0 = *(const float4*)&wsm[kk][tx * 4];         // 2-way (free)
            float4 b1 = *(const float4*)&wsm[kk][128 + tx * 4];
            float av[4] = {a.x, a.y, a.z, a.w};
            float bv[8] = {b0.x, b0.y, b0.z, b0.w, b1.x, b1.y, b1.z, b1.w};
#pragma unroll
            for (int mi = 0; mi < 4; mi++)
#pragma unroll
                for (int j = 0; j < 8; j++)
                    accf[mi][j] = fmaf(av[mi], bv[j], accf[mi][j]);
        }

        // roll chunk into persistent f32 accumulators (two-level fp32, R8-proven)
#pragma unroll
        for (int mi = 0; mi < 4; mi++)
#pragma unroll
            for (int j = 0; j < 8; j++) accd[mi][j] += accf[mi][j];
    }

    // epilogue: add bias, sigmoid in f64, store
#pragma unroll
    for (int mi = 0; mi < 4; mi++) {
        const size_t row = (size_t)(m0 + ty * 4 + mi) * NE;
#pragma unroll
        for (int j = 0; j < 8; j++) {
            const int n = (j < 4) ? (tx * 4 + j) : (128 + tx * 4 + (j - 4));
            double z = (double)accd[mi][j] + (double)bias[n];
            double s = 1.0 / (1.0 + exp(-z));
            sd[row + n] = s;
        }
    }
}

// ---------------------------------------------------------------------------
// Kernel B: grouped routing. One wave (64 lanes) per token; lane l owns
// experts [4l, 4l+3]; group g = experts [32g, 32g+31] = lanes [8g, 8g+7].
// (unchanged — proven correct since round 2)
// ---------------------------------------------------------------------------
__global__ __launch_bounds__(256) void route_kernel(
    const double* __restrict__ sd, const float* __restrict__ bias,
    float* __restrict__ wout, float* __restrict__ iout)
{
    const int lane = threadIdx.x & 63;
    const int wid  = threadIdx.x >> 6;
    const int tok  = blockIdx.x * 4 + wid;
    const double* srow = sd + (size_t)tok * NE;
    const int e0 = lane * 4;

    const double NEG = -__builtin_inf();

    double s0 = srow[e0 + 0], s1 = srow[e0 + 1], s2 = srow[e0 + 2], s3 = srow[e0 + 3];
    double sb0 = s0 + (double)bias[e0 + 0];
    double sb1 = s1 + (double)bias[e0 + 1];
    double sb2 = s2 + (double)bias[e0 + 2];
    double sb3 = s3 + (double)bias[e0 + 3];

    // per-lane top-2 of 4
    double m1 = sb0, m2 = NEG;
    if (sb1 > m1) { m2 = m1; m1 = sb1; } else if (sb1 > m2) m2 = sb1;
    if (sb2 > m1) { m2 = m1; m1 = sb2; } else if (sb2 > m2) m2 = sb2;
    if (sb3 > m1) { m2 = m1; m1 = sb3; } else if (sb3 > m2) m2 = sb3;

    // 8-lane butterfly merge of top-2 pairs (within group)
#pragma unroll
    for (int mask = 1; mask <= 4; mask <<= 1) {
        double o1 = __shfl_xor(m1, mask);
        double o2 = __shfl_xor(m2, mask);
        double n1 = fmax(m1, o1);
        double n2 = fmax(fmin(m1, o1), fmax(m2, o2));
        m1 = n1; m2 = n2;
    }
    double gs = m1 + m2;   // group score

    double g[8];
#pragma unroll
    for (int j = 0; j < 8; j++) g[j] = __shfl(gs, j * 8);

    const int myg = lane >> 3;
    int rank = 0;
#pragma unroll
    for (int j = 0; j < 8; j++)
        rank += (g[j] > g[myg] || (g[j] == g[myg] && j < myg)) ? 1 : 0;
    const bool keep = (rank < TOPG);

    double v0 = keep ? sb0 : NEG;
    double v1 = keep ? sb1 : NEG;
    double v2 = keep ? sb2 : NEG;
    double v3 = keep ? sb3 : NEG;

    double wv[TOPKK];
    int    idx[TOPKK];

#pragma unroll
    for (int r = 0; r < TOPKK; r++) {
        double bvv = v0; int bi = e0;
        if (v1 > bvv) { bvv = v1; bi = e0 + 1; }
        if (v2 > bvv) { bvv = v2; bi = e0 + 2; }
        if (v3 > bvv) { bvv = v3; bi = e0 + 3; }
#pragma unroll
        for (int mask = 1; mask <= 32; mask <<= 1) {
            double ov = __shfl_xor(bvv, mask);
            int    oi = __shfl_xor(bi, mask);
            if (ov > bvv || (ov == bvv && oi < bi)) { bvv = ov; bi = oi; }
        }
        const int sel   = bi & 3;
        const int owner = bi >> 2;
        double cands = (sel == 0) ? s0 : (sel == 1) ? s1 : (sel == 2) ? s2 : s3;
        wv[r]  = __shfl(cands, owner);
        idx[r] = bi;
        if (lane == owner) {
            if (sel == 0) v0 = NEG;
            else if (sel == 1) v1 = NEG;
            else if (sel == 2) v2 = NEG;
            else v3 = NEG;
        }
    }

    double sum = 0.0;
#pragma unroll
    for (int r = 0; r < TOPKK; r++) sum += wv[r];
    const double scale = 2.5 / sum;

    if (lane == 0) {
#pragma unroll
        for (int r = 0; r < TOPKK; r++)
            wout[(size_t)tok * TOPKK + r] = (float)(wv[r] * scale);
#pragma unroll
        for (int r = 0; r < TOPKK; r++)
            iout[(size_t)tok * TOPKK + r] = (float)idx[r];
    }
}

// ---------------------------------------------------------------------------
extern "C" void kernel_launch(void* const* d_in, const int* in_sizes, int n_in,
                              void* d_out, int out_size, void* d_ws, size_t ws_size,
                              hipStream_t stream) {
    const float* x = (const float*)d_in[0];
    const float* w = (const float*)d_in[1];
    const float* b = (const float*)d_in[2];

    double* sd = (double*)d_ws;                 // [NT][NE] f64 sigmoid scores (32 MB)
    float* wout = (float*)d_out;                // [NT][8] weights
    float* iout = wout + (size_t)NT * TOPKK;    // [NT][8] indices stored as float

    score_kernel<<<NT / BM, 512, 0, stream>>>(x, w, b, sd);
    route_kernel<<<NT / 4, 256, 0, stream>>>(sd, b, wout, iout);
}